// Round 2
// 210.401 us; speedup vs baseline: 1.0118x; 1.0118x over previous
//
#include <hip/hip_runtime.h>
#include <math.h>

#define B_ 32
#define K_ 17
#define H_ 128
#define W_ 128
#define HW_ (H_ * W_)            // 16384
#define C_PAF_ 38
#define NE_ 19
#define HM_BLOCKS 544            // one block per (b,k) full tile (64 KB/stream)
#define PAF_BLOCKS 1216          // 1216 * 4096 float4 == PAF_N4 exactly
#define GRID (HM_BLOCKS + PAF_BLOCKS)   // 1760 <= 2048 co-resident @ 8 blk/CU
#define THREADS 256
#define FT 576                   // final kernel threads (9 waves)
#define PAF_N ((size_t)B_ * C_PAF_ * H_ * W_)   // 19922944
#define PAF_N4 (PAF_N / 4)                      // 4980736

typedef float fvec4 __attribute__((ext_vector_type(4)));

__constant__ int c_edge_a[NE_] = {15,13,16,14,11, 5, 6, 5, 5, 6, 7, 8, 1, 0, 0, 1, 2, 3, 4};
__constant__ int c_edge_b[NE_] = {13,11,14,12,12,11,12, 6, 7, 8, 9,10, 2, 1, 2, 3, 4, 5, 6};

// ws layout (floats/ints in one buffer, disjoint index ranges)
#define WS_SSQ 0                 // float[544]  per-tile ssq
#define WS_IDX (HM_BLOCKS)       // int[544]    per-tile argmax index (0..16383)
#define WS_PAF (2 * HM_BLOCKS)   // float[1216] paf ssq partials

// Balanced grid: every block streams exactly 128 KB (64 KB from each of two
// buffers), contiguous. All 1760 blocks co-resident -> single dispatch wave.
// Blocks [0, 544): full-tile heatmap ssq + argmax.
// Blocks [544, 1760): paf ssq partials (4096 float4 per stream).
__global__ __launch_bounds__(THREADS, 8) void pose_reduce_kernel(
    const float* __restrict__ hm_pred, const float* __restrict__ hm_gt,
    const float* __restrict__ paf_pred, const float* __restrict__ paf_gt,
    float* __restrict__ ws_f, int* __restrict__ ws_i)
{
    __shared__ float s_val[4];
    __shared__ float s_ssq[4];
    __shared__ int   s_idx[4];

    const int t = threadIdx.x;
    const int bid = blockIdx.x;
    const int wave = t >> 6;
    const int lane = t & 63;

    if (bid < HM_BLOCKS) {
        const size_t off = (size_t)bid * HW_;
        const fvec4* __restrict__ p = (const fvec4*)(hm_pred + off);
        const fvec4* __restrict__ g = (const fvec4*)(hm_gt   + off);
        float ssq[2] = {0.0f, 0.0f};
        float m[2] = {-INFINITY, -INFINITY};
        int mi[2] = {0, 0};
        // 16 float4/thread per stream; unroll-by-4 keeps straight-line load
        // count identical to the previously verified 64 KB kernel body.
        #pragma unroll 4
        for (int ob = 0; ob < 8; ++ob) {
            const int v0 = t + (ob * 2 + 0) * THREADS;
            const int v1 = t + (ob * 2 + 1) * THREADS;
            const fvec4 a0 = __builtin_nontemporal_load(p + v0);
            const fvec4 b0 = __builtin_nontemporal_load(g + v0);
            const fvec4 a1 = __builtin_nontemporal_load(p + v1);
            const fvec4 b1 = __builtin_nontemporal_load(g + v1);
            {
                const float d0 = a0.x - b0.x, d1 = a0.y - b0.y;
                const float d2 = a0.z - b0.z, d3 = a0.w - b0.w;
                ssq[0] += d0 * d0 + d1 * d1 + d2 * d2 + d3 * d3;
                float m4 = a0.x; int k4 = 0;
                if (a0.y > m4) { m4 = a0.y; k4 = 1; }
                if (a0.z > m4) { m4 = a0.z; k4 = 2; }
                if (a0.w > m4) { m4 = a0.w; k4 = 3; }
                if (m4 > m[0]) { m[0] = m4; mi[0] = 4 * v0 + k4; }
            }
            {
                const float d0 = a1.x - b1.x, d1 = a1.y - b1.y;
                const float d2 = a1.z - b1.z, d3 = a1.w - b1.w;
                ssq[1] += d0 * d0 + d1 * d1 + d2 * d2 + d3 * d3;
                float m4 = a1.x; int k4 = 0;
                if (a1.y > m4) { m4 = a1.y; k4 = 1; }
                if (a1.z > m4) { m4 = a1.z; k4 = 2; }
                if (a1.w > m4) { m4 = a1.w; k4 = 3; }
                if (m4 > m[1]) { m[1] = m4; mi[1] = 4 * v1 + k4; }
            }
        }
        float sT = ssq[0] + ssq[1];
        float M; int MI;
        // slots interleave in index space; tie -> smaller index (first occurrence)
        if (m[1] > m[0] || (m[1] == m[0] && mi[1] < mi[0])) { M = m[1]; MI = mi[1]; }
        else { M = m[0]; MI = mi[0]; }
        #pragma unroll
        for (int off2 = 32; off2 > 0; off2 >>= 1) {
            const float m2  = __shfl_down(M,  off2);
            const int   mi2 = __shfl_down(MI, off2);
            const float s2  = __shfl_down(sT, off2);
            sT += s2;
            if (m2 > M || (m2 == M && mi2 < MI)) { M = m2; MI = mi2; }
        }
        if (lane == 0) { s_val[wave] = M; s_idx[wave] = MI; s_ssq[wave] = sT; }
        __syncthreads();
        if (t == 0) {
            #pragma unroll
            for (int wv = 1; wv < 4; ++wv) {
                sT += s_ssq[wv];
                if (s_val[wv] > M || (s_val[wv] == M && s_idx[wv] < MI)) {
                    M = s_val[wv]; MI = s_idx[wv];
                }
            }
            ws_f[WS_SSQ + bid] = sT;
            ws_i[WS_IDX + bid] = MI;     // full-tile index, no half merge needed
        }
    } else {
        const int pb = bid - HM_BLOCKS;
        const fvec4* __restrict__ p = (const fvec4*)paf_pred + (size_t)pb * 4096;
        const fvec4* __restrict__ g = (const fvec4*)paf_gt   + (size_t)pb * 4096;
        float ssq[2] = {0.0f, 0.0f};
        #pragma unroll 4
        for (int ob = 0; ob < 8; ++ob) {
            const int v0 = t + (ob * 2 + 0) * THREADS;
            const int v1 = t + (ob * 2 + 1) * THREADS;
            const fvec4 a0 = __builtin_nontemporal_load(p + v0);
            const fvec4 b0 = __builtin_nontemporal_load(g + v0);
            const fvec4 a1 = __builtin_nontemporal_load(p + v1);
            const fvec4 b1 = __builtin_nontemporal_load(g + v1);
            {
                const float d0 = a0.x - b0.x, d1 = a0.y - b0.y;
                const float d2 = a0.z - b0.z, d3 = a0.w - b0.w;
                ssq[0] += d0 * d0 + d1 * d1 + d2 * d2 + d3 * d3;
            }
            {
                const float d0 = a1.x - b1.x, d1 = a1.y - b1.y;
                const float d2 = a1.z - b1.z, d3 = a1.w - b1.w;
                ssq[1] += d0 * d0 + d1 * d1 + d2 * d2 + d3 * d3;
            }
        }
        float sT = ssq[0] + ssq[1];
        #pragma unroll
        for (int off2 = 32; off2 > 0; off2 >>= 1) sT += __shfl_down(sT, off2);
        if (lane == 0) s_ssq[wave] = sT;
        __syncthreads();
        if (t == 0) ws_f[WS_PAF + pb] = (s_ssq[0] + s_ssq[1]) + (s_ssq[2] + s_ssq[3]);
    }
}

// 576 threads: phase A loads all per-(b,k) stats + coords coalesced into LDS
// (short dependent-load chains), phase B does top-8 + skeleton from LDS only.
__global__ __launch_bounds__(FT) void pose_final_kernel(
    const float* __restrict__ ws_f, const int* __restrict__ ws_i,
    const int* __restrict__ coords, float* __restrict__ out)
{
    __shared__ float s_lk[HM_BLOCKS];
    __shared__ float s_px[HM_BLOCKS];
    __shared__ float s_py[HM_BLOCKS];
    __shared__ float s_gx[HM_BLOCKS];
    __shared__ float s_gy[HM_BLOCKS];
    __shared__ float s_p[FT / 64];

    const int t = threadIdx.x;
    const int wave = t >> 6;
    const int lane = t & 63;

    // --- paf partial sum (1216 values across 576 threads) ---
    float ps = 0.0f;
    for (int i = t; i < PAF_BLOCKS; i += FT) ps += ws_f[WS_PAF + i];
    #pragma unroll
    for (int off = 32; off > 0; off >>= 1) ps += __shfl_down(ps, off);
    if (lane == 0) s_p[wave] = ps;

    // --- per-(b,k): ssq -> per-kp loss, argmax idx -> (px,py), coords -> LDS ---
    if (t < HM_BLOCKS) {
        s_lk[t] = ws_f[WS_SSQ + t] * (1.0f / (float)HW_);
        const int idx = ws_i[WS_IDX + t];
        s_px[t] = (float)(idx & (W_ - 1));
        s_py[t] = (float)(idx >> 7);
        s_gx[t] = (float)coords[2 * t];
        s_gy[t] = (float)coords[2 * t + 1];
    }
    __syncthreads();

    // --- per-batch: top-8 + skeleton loss, all from LDS ---
    float val = 0.0f;
    if (t < B_) {
        const int base = t * K_;
        float lk[K_];
        #pragma unroll
        for (int k = 0; k < K_; ++k) lk[k] = s_lk[base + k];
        float tsum = 0.0f;
        for (int jj = 0; jj < 8; ++jj) {     // top-8 selection (sum only)
            int best = 0; float bv = lk[0];
            #pragma unroll
            for (int k = 1; k < K_; ++k) if (lk[k] > bv) { bv = lk[k]; best = k; }
            tsum += bv;
            lk[best] = -INFINITY;
        }
        float s = 0.0f;
        #pragma unroll
        for (int e = 0; e < NE_; ++e) {
            const int ea = base + c_edge_a[e], eb = base + c_edge_b[e];
            const float dx = s_px[ea] - s_px[eb];
            const float dy = s_py[ea] - s_py[eb];
            const float plen = sqrtf(dx * dx + dy * dy);
            const float gx = s_gx[ea] - s_gx[eb];
            const float gy = s_gy[ea] - s_gy[eb];
            const float glen = sqrtf(gx * gx + gy * gy);
            const float d = plen - glen;
            s += d * d;
        }
        val = tsum * (1.0f / 8.0f) + s / (19.0f + 1e-6f);
    }
    #pragma unroll
    for (int off = 16; off > 0; off >>= 1) val += __shfl_down(val, off);
    if (t == 0) {
        float paf_sum = 0.0f;
        #pragma unroll
        for (int wv = 0; wv < FT / 64; ++wv) paf_sum += s_p[wv];
        out[0] = val * (1.0f / (float)B_) + paf_sum * (1.0f / (float)PAF_N);
    }
}

extern "C" void kernel_launch(void* const* d_in, const int* in_sizes, int n_in,
                              void* d_out, int out_size, void* d_ws, size_t ws_size,
                              hipStream_t stream) {
    const float* hm_pred  = (const float*)d_in[0];
    const float* paf_pred = (const float*)d_in[1];
    const float* hm_gt    = (const float*)d_in[2];
    const float* paf_gt   = (const float*)d_in[3];
    const int*   coords   = (const int*)d_in[4];
    float* out = (float*)d_out;

    float* ws_f = (float*)d_ws;
    int*   ws_i = (int*)d_ws;   // disjoint index ranges within the same buffer

    pose_reduce_kernel<<<GRID, THREADS, 0, stream>>>(
        hm_pred, hm_gt, paf_pred, paf_gt, ws_f, ws_i);
    pose_final_kernel<<<1, FT, 0, stream>>>(ws_f, ws_i, coords, out);
}